// Round 1
// baseline (265.167 us; speedup 1.0000x reference)
//
#include <hip/hip_runtime.h>

// Faster-RCNN box-head postprocess, 5 regular dispatches.
// Bound used: M100 = 100th-largest per-row max key <= T (100th-largest entry),
// so a threshold from the P row-max keys lower-bounds T; rows with
// maxk >= lb contain the whole top-100. Candidates >= lb are then refined with
// an entry-level 12-bit histogram to shrink the final bitonic sort.
// K0: zero per-image row-max histograms + candidate counters.
// K1: per-row softmax offset + max fg score key (1 expf for the key, monotone);
//     also builds the per-image 4096-bin row-max histogram via global atomics.
// K2a (8 blocks/image): lb from prebuilt hist -> hot rows in slice -> collect
//     candidate entries >= lb into per-image global array (parallel across 64 CUs).
// K2b (1 block/image): entry hist -> lb_ent -> compact -> bitonic sort -> decode.
// K3: parallel feature gather.
#define NCLS 91
#define NFG 90
#define NDET 100
#define FDIM 1024
#define NBUK 4096
#define CAP_G 8192          // per-image global candidate capacity
#define CAP_L 4096          // LDS sort capacity in K2b
#define HOT_CAP 2048
#define BBOX_CLIP 4.135166556742356f
#define K1_TPB 256
#define RPB 32              // rows per K1 block (8 per wave)
#define K2_TPB 1024
#define GPB 8               // collect blocks per image

// ---------------- K0: zero hist + counters ----------------
__global__ __launch_bounds__(256) void k0_zero(unsigned* __restrict__ p, int n) {
    int i = blockIdx.x * 256 + threadIdx.x;
    if (i < n) p[i] = 0u;
}

// ---------------- K1: softmax offset + per-row max fg key + row hist ----------------
__global__ __launch_bounds__(K1_TPB) void k1_soft(
        const float* __restrict__ logits, float* __restrict__ rowoff,
        unsigned* __restrict__ maxk, unsigned* __restrict__ ghist,
        int N, int P) {
    int wave = threadIdx.x >> 6, lane = threadIdx.x & 63;
    int rowbase = blockIdx.x * RPB + wave * (RPB / 4);
    for (int it = 0; it < RPB / 4; it++) {
        long long row = rowbase + it;
        if (row >= N) return;
        const float* r = logits + row * NCLS;
        float l1 = r[lane];                              // classes 0..63
        float l2 = (lane < NCLS - 64) ? r[64 + lane] : -INFINITY;  // 64..90
        // fg max first; global max = fmax(fg max, class-0 logit)
        float mf = fmaxf((lane == 0) ? -INFINITY : l1, l2);
        #pragma unroll
        for (int o = 32; o; o >>= 1) mf = fmaxf(mf, __shfl_xor(mf, o));
        float m = fmaxf(mf, __shfl(l1, 0));              // bitwise same as full max
        float e = expf(l1 - m) + ((lane < NCLS - 64) ? expf(l2 - m) : 0.0f);
        #pragma unroll
        for (int o = 32; o; o >>= 1) e += __shfl_xor(e, o);
        float off = m + logf(e);                         // same bits all lanes
        // expf monotone => key of max fg logit == max over fg entry keys
        unsigned km = __float_as_uint(expf(mf - off));
        if (lane == 0) {
            rowoff[row] = off; maxk[row] = km;
            int img = (int)(row / P);
            atomicAdd(&ghist[img * NBUK + (km >> 20)], 1u);
        }
    }
}

// Parallel suffix-scan threshold finder over a 4096-bucket histogram (LDS or
// global). tid<256 threads own 16 buckets each; finds lb = floor of highest
// bucket b where count(keys >= b) crosses `target` from above. All threads
// must call.
__device__ __forceinline__ void find_threshold(const unsigned* hist,
                                               unsigned* wsum, unsigned* sh_lb,
                                               int tid, unsigned target) {
    unsigned local[16]; unsigned s = 0, run = 0;
    if (tid < 256) {
        #pragma unroll
        for (int i = 0; i < 16; i++) { local[i] = hist[tid * 16 + i]; s += local[i]; }
        run = s;
        #pragma unroll
        for (int off = 1; off < 64; off <<= 1) {     // in-wave inclusive suffix
            unsigned v = __shfl_down(run, off);
            if ((tid & 63) + off < 64) run += v;
        }
        if ((tid & 63) == 0) wsum[tid >> 6] = run;   // 4 wave totals
    }
    __syncthreads();
    if (tid < 256) {
        int w = tid >> 6;
        #pragma unroll
        for (int ww = 0; ww < 4; ww++) if (ww > w) run += wsum[ww];
        unsigned above = run - s;                    // strictly above my chunk
        #pragma unroll
        for (int i = 15; i >= 0; i--) {
            unsigned prev = above; above += local[i];
            if (above >= target && prev < target)
                *sh_lb = ((unsigned)(tid * 16 + i)) << 20;
        }
    }
    __syncthreads();
}

// ---------------- K2a: per-slice hot-row collect (8 blocks per image) ----------------
__global__ __launch_bounds__(K2_TPB) void k2a_collect(
        const float* __restrict__ logits, const float* __restrict__ rowoff,
        const unsigned* __restrict__ maxk, const unsigned* __restrict__ ghist,
        unsigned long long* __restrict__ gcand, unsigned* __restrict__ gcnt,
        int P) {
    __shared__ unsigned hot[HOT_CAP];   // 8 KB
    __shared__ unsigned wsum[4];
    __shared__ unsigned sh_lb, sh_nhot;

    const int img = blockIdx.x / GPB, sub = blockIdx.x % GPB;
    const int tid = threadIdx.x;
    if (tid == 0) { sh_lb = 0; sh_nhot = 0; }
    // threshold from the prebuilt per-image row-max histogram (global reads;
    // identical integer data in every block of this image -> identical lb)
    find_threshold(ghist + (size_t)img * NBUK, wsum, &sh_lb, tid, NDET);
    const unsigned lb = sh_lb;          // lb <= M100 <= T
    const unsigned lbh = lb ? lb - 1 : 0;   // 1-ulp slack for maxk monotonicity

    // --- hot rows in my slice: maxk >= lb-1 (coalesced scan) ---
    const int chunk = (P + GPB - 1) / GPB;
    const int r0 = sub * chunk;
    const int r1 = (r0 + chunk < P) ? (r0 + chunk) : P;
    const unsigned* mk = maxk + (size_t)img * P;
    for (int r = r0 + tid; r < r1; r += K2_TPB)
        if (mk[r] >= lbh) {
            unsigned p = atomicAdd(&sh_nhot, 1u);
            if (p < HOT_CAP) hot[p] = (unsigned)r;
        }
    __syncthreads();
    int nhot = (int)sh_nhot; if (nhot > HOT_CAP) nhot = HOT_CAP;

    // --- collect entries >= lb from hot rows (wave per row) into global ---
    const int wave = tid >> 6, lane = tid & 63;
    unsigned long long* gc = gcand + (size_t)img * CAP_G;
    for (int i = wave; i < nhot; i += K2_TPB / 64) {
        int rl = (int)hot[i];
        long long row = (long long)img * P + rl;
        float off = rowoff[row];
        const float* r = logits + row * NCLS;
        float l1 = r[lane];
        float l2 = (lane < NCLS - 64) ? r[64 + lane] : -INFINITY;
        if (lane >= 1) {
            unsigned k = __float_as_uint(expf(l1 - off));
            if (k >= lb) {
                unsigned pos = atomicAdd(&gcnt[img], 1u);
                if (pos < CAP_G)
                    gc[pos] = ((unsigned long long)k << 32) |
                              (unsigned)(0xFFFFFFFFu - (unsigned)(rl * NFG + lane - 1));
            }
        }
        if (lane < NCLS - 64) {
            unsigned k = __float_as_uint(expf(l2 - off));
            if (k >= lb) {
                unsigned pos = atomicAdd(&gcnt[img], 1u);
                if (pos < CAP_G)
                    gc[pos] = ((unsigned long long)k << 32) |
                              (unsigned)(0xFFFFFFFFu - (unsigned)(rl * NFG + 63 + lane));
            }
        }
    }
}

// ---------------- K2b: per-image refine + sort + decode ----------------
__global__ __launch_bounds__(K2_TPB) void k2b_sort(
        const float* __restrict__ reg, const float* __restrict__ props,
        const int* __restrict__ pH, const int* __restrict__ pW,
        const unsigned long long* __restrict__ gcand,
        const unsigned* __restrict__ gcnt,
        float* __restrict__ outBoxes, unsigned* __restrict__ keepRow, int P) {
    __shared__ unsigned long long cand[CAP_L];  // 32 KB
    __shared__ unsigned hist[NBUK];             // 16 KB
    __shared__ unsigned wsum[4];
    __shared__ unsigned sh_lb2, sh_n2;

    const int img = blockIdx.x, tid = threadIdx.x;
    if (tid == 0) { sh_lb2 = 0; sh_n2 = 0; }
    for (int b = tid; b < NBUK; b += K2_TPB) hist[b] = 0u;
    __syncthreads();

    unsigned cnt = gcnt[img]; if (cnt > CAP_G) cnt = CAP_G;
    const unsigned long long* gc = gcand + (size_t)img * CAP_G;

    // --- entry-level refinement: 12-bit hist of candidate keys -> lb_ent ---
    for (int i = tid; i < (int)cnt; i += K2_TPB)
        atomicAdd(&hist[(unsigned)(gc[i] >> 52)], 1u);
    __syncthreads();
    find_threshold(hist, wsum, &sh_lb2, tid, NDET);
    const unsigned lb2 = sh_lb2;        // count(keys >= lb2) >= NDET
    // --- compact keys >= lb2 into LDS ---
    for (int i = tid; i < (int)cnt; i += K2_TPB) {
        unsigned long long k64 = gc[i];
        if ((unsigned)(k64 >> 32) >= lb2) {
            unsigned pos = atomicAdd(&sh_n2, 1u);
            if (pos < CAP_L) cand[pos] = k64;
        }
    }
    __syncthreads();
    unsigned cnt2 = sh_n2; if (cnt2 > CAP_L) cnt2 = CAP_L;
    int n = 128; while (n < (int)cnt2) n <<= 1;
    for (int i = tid; i < n; i += K2_TPB) if (i >= (int)cnt2) cand[i] = 0ULL;
    __syncthreads();

    // --- ascending bitonic sort of n keys; top-100 at n-1 .. n-100 ---
    // (keys are unique: low word packs ~entry index -> deterministic result
    //  regardless of cross-block candidate arrival order)
    for (int k = 2; k <= n; k <<= 1) {
        for (int j = k >> 1; j > 0; j >>= 1) {
            for (int i = tid; i < n; i += K2_TPB) {
                int ixj = i ^ j;
                if (ixj > i) {
                    bool up = ((i & k) == 0);
                    unsigned long long a = cand[i], b = cand[ixj];
                    if ((a > b) == up) { cand[i] = b; cand[ixj] = a; }
                }
            }
            __syncthreads();
        }
    }

    // --- decode + clip + normalize top-100 boxes; record feature rows ---
    if (tid < NDET) {
        unsigned long long key = cand[n - 1 - tid];
        unsigned e = 0xFFFFFFFFu - (unsigned)(key & 0xFFFFFFFFull);
        int pr = e / NFG, cm = e - pr * NFG, c = cm + 1;
        long long rw = (long long)img * P + pr;
        float x1 = props[rw * 4 + 0], y1 = props[rw * 4 + 1];
        float x2 = props[rw * 4 + 2], y2 = props[rw * 4 + 3];
        float w = x2 - x1, hgt = y2 - y1;
        float cx = x1 + 0.5f * w, cy = y1 + 0.5f * hgt;
        const float* rr = reg + rw * (4 * NCLS) + 4 * c;
        float dx = rr[0] / 10.0f, dy = rr[1] / 10.0f;
        float dw = fminf(rr[2] / 5.0f, BBOX_CLIP);
        float dh = fminf(rr[3] / 5.0f, BBOX_CLIP);
        float pcx = dx * w + cx, pcy = dy * hgt + cy;
        float pw_ = expf(dw) * w, ph_ = expf(dh) * hgt;
        float bx1 = pcx - 0.5f * pw_, by1 = pcy - 0.5f * ph_;
        float bx2 = pcx + 0.5f * pw_, by2 = pcy + 0.5f * ph_;
        float W = (float)(*pW), H = (float)(*pH);
        bx1 = fminf(fmaxf(bx1, 0.0f), W);
        bx2 = fminf(fmaxf(bx2, 0.0f), W);
        by1 = fminf(fmaxf(by1, 0.0f), H);
        by2 = fminf(fmaxf(by2, 0.0f), H);
        int o = (img * NDET + tid) * 4;
        outBoxes[o + 0] = bx1 / H;
        outBoxes[o + 1] = by1 / H;
        outBoxes[o + 2] = bx2 / H;
        outBoxes[o + 3] = by2 / H;
        keepRow[img * NDET + tid] = (unsigned)rw;
    }
}

// ---------------- K3: feature gather (1 det per block, float4) ----------------
__global__ __launch_bounds__(256) void k3_feats(
        const float* __restrict__ feats, const unsigned* __restrict__ keepRow,
        float* __restrict__ outF) {
    int det = blockIdx.x;
    long long r = keepRow[det];
    const float4* src = (const float4*)(feats + r * FDIM);
    float4* dst = (float4*)(outF + (long long)det * FDIM);
    dst[threadIdx.x] = src[threadIdx.x];
}

extern "C" void kernel_launch(void* const* d_in, const int* in_sizes, int n_in,
                              void* d_out, int out_size, void* d_ws, size_t ws_size,
                              hipStream_t stream) {
    const float* logits = (const float*)d_in[0];
    const float* reg    = (const float*)d_in[1];
    const float* props  = (const float*)d_in[2];
    const float* feats  = (const float*)d_in[3];
    const int*   pH     = (const int*)d_in[5];
    const int*   pW     = (const int*)d_in[6];

    int N = in_sizes[0] / NCLS;               // total proposals (B*P)
    int B = out_size / (NDET * (4 + FDIM));   // 8
    int P = N / B;

    // workspace: gcand [B*CAP_G] u64 | rowoff [N] f32 | maxk [N] u32 |
    //            keepRow [B*NDET] u32 | ghist [B*NBUK] u32 | gcnt [B] u32
    char* ws = (char*)d_ws;
    unsigned long long* gcand = (unsigned long long*)ws;
    float*    rowoff  = (float*)(gcand + (size_t)B * CAP_G);
    unsigned* maxk    = (unsigned*)(rowoff + N);
    unsigned* keepRow = (unsigned*)(maxk + N);
    unsigned* ghist   = keepRow + (size_t)B * NDET;
    unsigned* gcnt    = ghist + (size_t)B * NBUK;

    float* outBoxes = (float*)d_out;
    float* outFeats = outBoxes + (size_t)B * NDET * 4;

    int nzero = B * NBUK + B;
    k0_zero<<<(nzero + 255) / 256, 256, 0, stream>>>(ghist, nzero);
    k1_soft<<<(N + RPB - 1) / RPB, K1_TPB, 0, stream>>>(logits, rowoff, maxk,
                                                        ghist, N, P);
    k2a_collect<<<B * GPB, K2_TPB, 0, stream>>>(logits, rowoff, maxk, ghist,
                                                gcand, gcnt, P);
    k2b_sort<<<B, K2_TPB, 0, stream>>>(reg, props, pH, pW, gcand, gcnt,
                                       outBoxes, keepRow, P);
    k3_feats<<<B * NDET, 256, 0, stream>>>(feats, keepRow, outFeats);
}